// Round 6
// baseline (1551.885 us; speedup 1.0000x reference)
//
#include <hip/hip_runtime.h>
#include <cstdint>
#include <cstddef>

typedef __attribute__((ext_vector_type(8))) short short8;
typedef __attribute__((ext_vector_type(4))) float floatx4;
typedef __attribute__((ext_vector_type(4))) int intx4;

__device__ __forceinline__ unsigned short f2bf(float f) {
    union { float f; unsigned int i; } v; v.f = f;
    unsigned int r = v.i + 0x7FFFu + ((v.i >> 16) & 1u);
    return (unsigned short)(r >> 16);
}
// relu that propagates NaN (fmaxf would silently map NaN->0 and hide bugs)
__device__ __forceinline__ float relu_keepnan(float v) {
    return v > 0.f ? v : (v == v ? 0.f : v);
}

// ---------------- f32 -> bf16 weight convert ----------------------------------------
__global__ __launch_bounds__(256) void k_cvt(
    const float* __restrict__ src, unsigned short* __restrict__ dst, int n) {
    int i = blockIdx.x * 256 + threadIdx.x;
    if (i < n) dst[i] = f2bf(src[i]);
}

// ------- precompute, laid out [layer][n][ch] for lane=channel kernels:
// lwc = (wre, wim, 2*Re(Cc), 2*Im(Cc)),  wt = w^128 (segment propagator)
__global__ __launch_bounds__(256) void k_precompute(
    const float* __restrict__ ldt, const float* __restrict__ lar,
    const float* __restrict__ aim, const float* __restrict__ cre,
    const float* __restrict__ cim, float4* __restrict__ lwc,
    float2* __restrict__ wt) {
    int idx = blockIdx.x * 256 + threadIdx.x;      // [4][512][32]
    int i = idx >> 14;
    int h = (idx >> 5) & 511;
    int n = idx & 31;
    float dt = expf(ldt[i * 512 + h]);
    float Are = -expf(lar[idx]);
    float Aim = aim[idx];
    float dre = dt * Are, dim = dt * Aim;
    float e = expf(dre);
    float wre = e * cosf(dim);
    float wim = e * sinf(dim);
    float emr = wre - 1.f, emi = wim;              // expm1(dtA)
    float inv = 1.f / (Are * Are + Aim * Aim);
    float fr = (emr * Are + emi * Aim) * inv;      // expm1(dtA)/A
    float fi = (emi * Are - emr * Aim) * inv;
    float cr = cre[idx], ci = cim[idx];
    float4 o;
    o.x = wre; o.y = wim;
    o.z = 2.f * (cr * fr - ci * fi);
    o.w = 2.f * (cr * fi + ci * fr);
    int oidx = (i * 32 + n) * 512 + h;             // [layer][n][ch]
    lwc[oidx] = o;
    float ar = wre, ai = wim;                      // w^128 by 7 squarings
#pragma unroll
    for (int k = 0; k < 7; ++k) {
        float nr = ar * ar - ai * ai;
        float ni = 2.f * ar * ai;
        ar = nr; ai = ni;
    }
    wt[oidx] = make_float2(ar, ai);
}

// ---------------- quantize (round-half-even) + transpose (B,C,L)f32 -> (J,C) bf16 ----
__global__ __launch_bounds__(256) void k_quant_transpose(
    const float* __restrict__ x, unsigned short* __restrict__ xq, int b0) {
    __shared__ unsigned short tile[64][65];
    const int bg = b0 + blockIdx.z, bl = blockIdx.z;
    const int c0 = blockIdx.y * 64, t0 = blockIdx.x * 64;
#pragma unroll
    for (int it = 0; it < 16; ++it) {
        int idx = it * 256 + threadIdx.x;
        int r = idx >> 6, cc = idx & 63;
        float f = x[(size_t)(bg * 512 + c0 + r) * 2048 + t0 + cc];
        float q = rintf(f * 64.f) * 0.015625f;     // jnp.round = half-to-even
        tile[r][cc] = f2bf(q);
    }
    __syncthreads();
#pragma unroll
    for (int it = 0; it < 16; ++it) {
        int idx = it * 256 + threadIdx.x;
        int r = idx >> 6, cc = idx & 63;           // r = t-local, cc = c-local
        xq[(size_t)(bl * 2048 + t0 + r) * 512 + c0 + cc] = tile[cc][r];
    }
}

// ---------------- bf16 MFMA GEMM: C[m,j] = sum_k A[m,k]*Bm[j,k], K=512 ---------------
// MODE 0: relu -> hf f32 (j,512)      MODE 2: relu -> d_out f32 (B,512,L)
template <int MODE>
__global__ __launch_bounds__(256, 2) void k_gemm(
    const unsigned short* __restrict__ A, const unsigned short* __restrict__ Bm,
    float* __restrict__ of32, int b0) {
    __shared__ __align__(16) unsigned short Al[128 * 72];
    __shared__ __align__(16) unsigned short Bl[128 * 72];
    const int tid = threadIdx.x;
    const int m0 = blockIdx.x * 128;
    const int j0 = blockIdx.y * 128;
    const int sub = tid & 7;
    const int row = tid >> 3;
    const unsigned short* Ag = A + (size_t)(m0 + row) * 512 + sub * 8;
    const unsigned short* Bg = Bm + (size_t)(j0 + row) * 512 + sub * 8;
    intx4 ra[4], rb[4];
#pragma unroll
    for (int i = 0; i < 4; ++i) {
        ra[i] = *(const intx4*)(Ag + (size_t)i * 32 * 512);
        rb[i] = *(const intx4*)(Bg + (size_t)i * 32 * 512);
    }
    const int lane = tid & 63;
    const int w = tid >> 6;
    const int wm = w & 1, wn = w >> 1;
    const int l15 = lane & 15, quad = lane >> 4;
    floatx4 acc[4][4] = {};
    for (int kt = 0; kt < 8; ++kt) {
#pragma unroll
        for (int i = 0; i < 4; ++i) {
            *(intx4*)(Al + (row + 32 * i) * 72 + sub * 8) = ra[i];
            *(intx4*)(Bl + (row + 32 * i) * 72 + sub * 8) = rb[i];
        }
        __syncthreads();
        if (kt < 7) {
#pragma unroll
            for (int i = 0; i < 4; ++i) {
                ra[i] = *(const intx4*)(Ag + (size_t)i * 32 * 512 + (kt + 1) * 64);
                rb[i] = *(const intx4*)(Bg + (size_t)i * 32 * 512 + (kt + 1) * 64);
            }
        }
#pragma unroll
        for (int ks = 0; ks < 2; ++ks) {
            short8 af[4], bfr[4];
#pragma unroll
            for (int mt = 0; mt < 4; ++mt)
                af[mt] = *(const short8*)(Al + (wm * 64 + mt * 16 + l15) * 72 + ks * 32 + quad * 8);
#pragma unroll
            for (int nt = 0; nt < 4; ++nt)
                bfr[nt] = *(const short8*)(Bl + (wn * 64 + nt * 16 + l15) * 72 + ks * 32 + quad * 8);
#pragma unroll
            for (int mt = 0; mt < 4; ++mt)
#pragma unroll
                for (int nt = 0; nt < 4; ++nt)
                    acc[mt][nt] = __builtin_amdgcn_mfma_f32_16x16x32_bf16(
                        af[mt], bfr[nt], acc[mt][nt], 0, 0, 0);
        }
        __syncthreads();
    }
#pragma unroll
    for (int mt = 0; mt < 4; ++mt) {
#pragma unroll
        for (int nt = 0; nt < 4; ++nt) {
            const int d = m0 + wm * 64 + mt * 16 + quad * 4;   // C/D row = quad*4+reg
            const int j = j0 + wn * 64 + nt * 16 + l15;        // C/D col = lane&15
            floatx4 v = acc[mt][nt];
            if (MODE == 0) {
#pragma unroll
                for (int r = 0; r < 4; ++r) v[r] = relu_keepnan(v[r]);
                *(floatx4*)(of32 + (size_t)j * 512 + d) = v;
            } else {
                const int bl = j >> 11, t = j & 2047;
#pragma unroll
                for (int r = 0; r < 4; ++r)
                    of32[((size_t)((b0 + bl) * 512 + d + r)) * 2048 + t] = relu_keepnan(v[r]);
            }
        }
    }
}

// ------- fused W_out GEMM + GLU: g_out[j,d] = (a+b1)*sigmoid(g+b2), both halves ------
__global__ __launch_bounds__(256, 2) void k_gemm_glu(
    const unsigned short* __restrict__ A,   // W_out layer (1024,512) bf16
    const unsigned short* __restrict__ Bm,  // vb (J,512) bf16
    const float* __restrict__ bias,         // b_out layer (1024) f32
    float* __restrict__ g_out) {            // (J,512) f32
    __shared__ __align__(16) unsigned short A1l[128 * 72];
    __shared__ __align__(16) unsigned short A2l[128 * 72];
    __shared__ __align__(16) unsigned short Bl[64 * 72];
    const int tid = threadIdx.x;
    const int m0 = blockIdx.x * 128;
    const int j0 = blockIdx.y * 64;
    const int sub = tid & 7;
    const int row = tid >> 3;                        // 0..31
    const unsigned short* A1g = A + (size_t)(m0 + row) * 512 + sub * 8;
    const unsigned short* A2g = A1g + 512 * 512;
    const unsigned short* Bg = Bm + (size_t)(j0 + row) * 512 + sub * 8;
    intx4 ra1[4], ra2[4], rb[2];
#pragma unroll
    for (int i = 0; i < 4; ++i) {
        ra1[i] = *(const intx4*)(A1g + (size_t)i * 32 * 512);
        ra2[i] = *(const intx4*)(A2g + (size_t)i * 32 * 512);
    }
#pragma unroll
    for (int i = 0; i < 2; ++i)
        rb[i] = *(const intx4*)(Bg + (size_t)i * 32 * 512);
    const int lane = tid & 63;
    const int w = tid >> 6;
    const int wm = w & 1, wn = w >> 1;               // 2x2 waves: m 2x64, n 2x32
    const int l15 = lane & 15, quad = lane >> 4;
    floatx4 ac1[4][2] = {}, ac2[4][2] = {};
    for (int kt = 0; kt < 8; ++kt) {
#pragma unroll
        for (int i = 0; i < 4; ++i) {
            *(intx4*)(A1l + (row + 32 * i) * 72 + sub * 8) = ra1[i];
            *(intx4*)(A2l + (row + 32 * i) * 72 + sub * 8) = ra2[i];
        }
#pragma unroll
        for (int i = 0; i < 2; ++i)
            *(intx4*)(Bl + (row + 32 * i) * 72 + sub * 8) = rb[i];
        __syncthreads();
        if (kt < 7) {
#pragma unroll
            for (int i = 0; i < 4; ++i) {
                ra1[i] = *(const intx4*)(A1g + (size_t)i * 32 * 512 + (kt + 1) * 64);
                ra2[i] = *(const intx4*)(A2g + (size_t)i * 32 * 512 + (kt + 1) * 64);
            }
#pragma unroll
            for (int i = 0; i < 2; ++i)
                rb[i] = *(const intx4*)(Bg + (size_t)i * 32 * 512 + (kt + 1) * 64);
        }
#pragma unroll
        for (int ks = 0; ks < 2; ++ks) {
            short8 af1[4], af2[4], bfr[2];
#pragma unroll
            for (int mt = 0; mt < 4; ++mt) {
                af1[mt] = *(const short8*)(A1l + (wm * 64 + mt * 16 + l15) * 72 + ks * 32 + quad * 8);
                af2[mt] = *(const short8*)(A2l + (wm * 64 + mt * 16 + l15) * 72 + ks * 32 + quad * 8);
            }
#pragma unroll
            for (int nt = 0; nt < 2; ++nt)
                bfr[nt] = *(const short8*)(Bl + (wn * 32 + nt * 16 + l15) * 72 + ks * 32 + quad * 8);
#pragma unroll
            for (int mt = 0; mt < 4; ++mt)
#pragma unroll
                for (int nt = 0; nt < 2; ++nt) {
                    ac1[mt][nt] = __builtin_amdgcn_mfma_f32_16x16x32_bf16(
                        af1[mt], bfr[nt], ac1[mt][nt], 0, 0, 0);
                    ac2[mt][nt] = __builtin_amdgcn_mfma_f32_16x16x32_bf16(
                        af2[mt], bfr[nt], ac2[mt][nt], 0, 0, 0);
                }
        }
        __syncthreads();
    }
#pragma unroll
    for (int mt = 0; mt < 4; ++mt) {
#pragma unroll
        for (int nt = 0; nt < 2; ++nt) {
            const int d = m0 + wm * 64 + mt * 16 + quad * 4;
            const int j = j0 + wn * 32 + nt * 16 + l15;
            floatx4 v;
#pragma unroll
            for (int r = 0; r < 4; ++r) {
                float a = ac1[mt][nt][r] + bias[d + r];
                float g = ac2[mt][nt][r] + bias[512 + d + r];
                v[r] = a / (1.f + expf(-g));
            }
            *(floatx4*)(g_out + (size_t)j * 512 + d) = v;
        }
    }
}

// ============ segmented S4D scan, one channel per lane, states in registers ==========
// 16 segments x 128 steps. Phase A: local end-state p (s0=0). Phase C: exclusive
// prefix s0[g] = w^128 s0[g-1] + p[g-1]. Phase B: re-scan seeded with s0, fused
// y-dot + D*u + gelu -> vb. Replaces DPP-reduce k_scan (R5: 218us, VALUBusy 94%).

// wave -> (b, chblk, seg); lane -> channel chblk*64+lane
__global__ __launch_bounds__(256, 2) void k_scan_state(
    const float* __restrict__ hbuf, const float4* __restrict__ lwc,
    float2* __restrict__ p, int layer) {
    const int wid = (blockIdx.x << 2) + (threadIdx.x >> 6);
    const int lane = threadIdx.x & 63;
    const int seg = wid & 15, chb = (wid >> 4) & 7, b = wid >> 7;
    const int ch = chb * 64 + lane;
    float wre[32], wim[32], sre[32], sim[32];
    const float4* wp = lwc + (size_t)(layer * 32) * 512 + ch;
#pragma unroll
    for (int n = 0; n < 32; ++n) {
        float4 v = wp[n * 512];
        wre[n] = v.x; wim[n] = v.y; sre[n] = 0.f; sim[n] = 0.f;
    }
    const float* ub = hbuf + ((size_t)b * 2048 + seg * 128) * 512 + ch;
    float unext = ub[0];
    for (int t = 0; t < 128; ++t) {
        float u = unext;
        if (t < 127) unext = ub[(t + 1) * 512];
#pragma unroll
        for (int n = 0; n < 32; ++n) {
            float t1 = fmaf(-wim[n], sim[n], u);
            float nr = fmaf(wre[n], sre[n], t1);
            float ni = fmaf(wim[n], sre[n], wre[n] * sim[n]);
            sre[n] = nr; sim[n] = ni;
        }
    }
    float2* pp = p + ((size_t)(b * 16 + seg) * 32) * 512 + ch;
#pragma unroll
    for (int n = 0; n < 32; ++n) pp[n * 512] = make_float2(sre[n], sim[n]);
}

// thread -> (b, n, ch): s0[g] = w128*s0[g-1] + p[g-1], exclusive
__global__ __launch_bounds__(256) void k_scan_comb(
    const float2* __restrict__ p, const float2* __restrict__ wt,
    float2* __restrict__ s0, int layer) {
    const int tid = blockIdx.x * 256 + threadIdx.x;
    const int ch = tid & 511, n = (tid >> 9) & 31, b = tid >> 14;
    const float2 wv = wt[(layer * 32 + n) * 512 + ch];
    const size_t base = ((size_t)(b * 16) * 32 + n) * 512 + ch;
    float ar = 0.f, ai = 0.f;
#pragma unroll
    for (int g = 0; g < 16; ++g) {
        s0[base + (size_t)g * 16384] = make_float2(ar, ai);
        float2 pv = p[base + (size_t)g * 16384];
        float nr = fmaf(wv.x, ar, fmaf(-wv.y, ai, pv.x));
        float ni = fmaf(wv.x, ai, fmaf(wv.y, ar, pv.y));
        ar = nr; ai = ni;
    }
}

__global__ __launch_bounds__(256, 2) void k_scan_apply(
    const float* __restrict__ hbuf, const float4* __restrict__ lwc,
    const float2* __restrict__ s0, const float* __restrict__ Dp,
    unsigned short* __restrict__ vout, int layer) {
    const int wid = (blockIdx.x << 2) + (threadIdx.x >> 6);
    const int lane = threadIdx.x & 63;
    const int seg = wid & 15, chb = (wid >> 4) & 7, b = wid >> 7;
    const int ch = chb * 64 + lane;
    float wre[32], wim[32], sre[32], sim[32], c2re[32], c2in[32];
    const float4* wp = lwc + (size_t)(layer * 32) * 512 + ch;
    const float2* sp = s0 + ((size_t)(b * 16 + seg) * 32) * 512 + ch;
#pragma unroll
    for (int n = 0; n < 32; ++n) {
        float4 v = wp[n * 512];
        wre[n] = v.x; wim[n] = v.y; c2re[n] = v.z; c2in[n] = -v.w;
        float2 sv = sp[n * 512];
        sre[n] = sv.x; sim[n] = sv.y;
    }
    const float Dh = Dp[layer * 512 + ch];
    const float* ub = hbuf + ((size_t)b * 2048 + seg * 128) * 512 + ch;
    unsigned short* vb = vout + ((size_t)b * 2048 + seg * 128) * 512 + ch;
    float unext = ub[0];
    for (int t = 0; t < 128; ++t) {
        float u = unext;
        if (t < 127) unext = ub[(t + 1) * 512];
        float y = 0.f;
#pragma unroll
        for (int n = 0; n < 32; ++n) {
            float t1 = fmaf(-wim[n], sim[n], u);
            float nr = fmaf(wre[n], sre[n], t1);
            float ni = fmaf(wim[n], sre[n], wre[n] * sim[n]);
            sre[n] = nr; sim[n] = ni;
            y = fmaf(c2re[n], nr, y);
            y = fmaf(c2in[n], ni, y);
        }
        y = fmaf(Dh, u, y);
        float g = 0.5f * y * (1.f + erff(y * 0.70710678118654752f));
        vb[t * 512] = f2bf(g);
    }
}

// ---------------- residual + LayerNorm over channels (g already GLU'd) ---------------
__global__ __launch_bounds__(256, 4) void k_res_ln(
    const float* __restrict__ g, float* __restrict__ hf, unsigned short* __restrict__ hb,
    const float* __restrict__ lng, const float* __restrict__ lnb,
    int layer, int wbf) {
    __shared__ float r1[4], r2[4];
    const size_t j = blockIdx.x;
    const float* gj = g + j * 512;
    float* hj = hf + j * 512;
    const int tid = threadIdx.x, lane = tid & 63, w = tid >> 6;
    float hn[2], s1 = 0.f, s2 = 0.f;
#pragma unroll
    for (int q = 0; q < 2; ++q) {
        int d = tid + q * 256;
        float v = gj[d] + hj[d];                  // residual
        hn[q] = v; s1 += v; s2 += v * v;
    }
#pragma unroll
    for (int m = 32; m >= 1; m >>= 1) { s1 += __shfl_xor(s1, m, 64); s2 += __shfl_xor(s2, m, 64); }
    if (lane == 0) { r1[w] = s1; r2[w] = s2; }
    __syncthreads();
    const float S1 = r1[0] + r1[1] + r1[2] + r1[3];
    const float S2 = r2[0] + r2[1] + r2[2] + r2[3];
    const float mu = S1 * (1.f / 512.f);
    const float var = S2 * (1.f / 512.f) - mu * mu;
    const float isd = 1.f / sqrtf(var + 1e-5f);
#pragma unroll
    for (int q = 0; q < 2; ++q) {
        int d = tid + q * 256;
        float o = (hn[q] - mu) * isd * lng[layer * 512 + d] + lnb[layer * 512 + d];
        hj[d] = o;
        if (wbf) hb[j * 512 + d] = f2bf(o);
    }
}

extern "C" void kernel_launch(void* const* d_in, const int* in_sizes, int n_in,
                              void* d_out, int out_size, void* d_ws, size_t ws_size,
                              hipStream_t stream) {
    (void)in_sizes; (void)n_in; (void)out_size;
    const float* x      = (const float*)d_in[0];
    const float* W_enc  = (const float*)d_in[1];
    const float* W_dec  = (const float*)d_in[2];
    const float* log_dt = (const float*)d_in[3];
    const float* log_Ar = (const float*)d_in[4];
    const float* A_im   = (const float*)d_in[5];
    const float* C_re   = (const float*)d_in[6];
    const float* C_im   = (const float*)d_in[7];
    const float* Dp     = (const float*)d_in[8];
    const float* W_out  = (const float*)d_in[9];
    const float* b_out  = (const float*)d_in[10];
    const float* ln_g   = (const float*)d_in[11];
    const float* ln_b   = (const float*)d_in[12];

    // fixed: lwc 1MiB + wt 0.5MiB + bf16 weights ~5MiB; per batch elem 10MiB
    int C = 16;
    while (C > 1 && (size_t)C * (10ull << 20) + (8ull << 20) > ws_size) C >>= 1;
    const size_t J = (size_t)C * 2048;

    char* ws = (char*)d_ws;
    size_t off = 0;
    auto alloc = [&](size_t bytes) { void* p = ws + off; off += (bytes + 255) & ~(size_t)255; return p; };
    float4*         lwc   = (float4*)alloc(4ull * 512 * 32 * 16);
    float2*         wt    = (float2*)alloc(4ull * 512 * 32 * 8);
    unsigned short* wencb = (unsigned short*)alloc(512 * 512 * 2);
    unsigned short* wdecb = (unsigned short*)alloc(512 * 512 * 2);
    unsigned short* woutb = (unsigned short*)alloc(4ull * 1024 * 512 * 2);
    float*          g     = (float*)alloc(J * 512 * 4);          // GLU out (xq/p/s0 alias)
    float*          hf    = (float*)alloc(J * 512 * 4);          // h, f32
    unsigned short* vb    = (unsigned short*)alloc(J * 512 * 2); // gelu out bf16 (hb alias)
    unsigned short* xq    = (unsigned short*)g;                  // dead after encoder GEMM
    unsigned short* hb    = vb;                                  // vb dead after layer-3 GEMM
    // scan scratch aliases g (dead during scan): p = C*2MiB, s0 = C*2MiB = exactly g
    float2*         p     = (float2*)g;
    float2*         s0    = (float2*)(g + (size_t)C * 524288);

    k_precompute<<<256, 256, 0, stream>>>(log_dt, log_Ar, A_im, C_re, C_im, lwc, wt);
    k_cvt<<<1024, 256, 0, stream>>>(W_enc, wencb, 512 * 512);
    k_cvt<<<1024, 256, 0, stream>>>(W_dec, wdecb, 512 * 512);
    k_cvt<<<8192, 256, 0, stream>>>(W_out, woutb, 4 * 1024 * 512);
    for (int b0 = 0; b0 < 16; b0 += C) {
        k_quant_transpose<<<dim3(32, 8, C), 256, 0, stream>>>(x, xq, b0);
        k_gemm<0><<<dim3(4, C * 16), 256, 0, stream>>>(wencb, xq, hf, 0);
        for (int i = 0; i < 4; ++i) {
            k_scan_state<<<C * 32, 256, 0, stream>>>(hf, lwc, p, i);
            k_scan_comb<<<C * 64, 256, 0, stream>>>(p, wt, s0, i);
            k_scan_apply<<<C * 32, 256, 0, stream>>>(hf, lwc, s0, Dp, vb, i);
            k_gemm_glu<<<dim3(4, C * 32), 256, 0, stream>>>(
                woutb + (size_t)i * 1024 * 512, vb, b_out + (size_t)i * 1024, g);
            k_res_ln<<<C * 2048, 256, 0, stream>>>(g, hf, hb, ln_g, ln_b, i, (i == 3) ? 1 : 0);
        }
        k_gemm<2><<<dim3(4, C * 16), 256, 0, stream>>>(wdecb, hb, (float*)d_out, b0);
    }
}

// Round 7
// 1319.192 us; speedup vs baseline: 1.1764x; 1.1764x over previous
//
#include <hip/hip_runtime.h>
#include <cstdint>
#include <cstddef>

typedef __attribute__((ext_vector_type(8))) short short8;
typedef __attribute__((ext_vector_type(4))) float floatx4;
typedef __attribute__((ext_vector_type(4))) int intx4;

__device__ __forceinline__ unsigned short f2bf(float f) {
    union { float f; unsigned int i; } v; v.f = f;
    unsigned int r = v.i + 0x7FFFu + ((v.i >> 16) & 1u);
    return (unsigned short)(r >> 16);
}
// relu that propagates NaN (fmaxf would silently map NaN->0 and hide bugs)
__device__ __forceinline__ float relu_keepnan(float v) {
    return v > 0.f ? v : (v == v ? 0.f : v);
}

// ---------------- f32 -> bf16 weight convert ----------------------------------------
__global__ __launch_bounds__(256) void k_cvt(
    const float* __restrict__ src, unsigned short* __restrict__ dst, int n) {
    int i = blockIdx.x * 256 + threadIdx.x;
    if (i < n) dst[i] = f2bf(src[i]);
}

// ------- precompute, laid out [layer][n][ch] for lane=channel kernels:
// lwc = (wre, wim, 2*Re(Cc), 2*Im(Cc)),  wt = w^128 (segment propagator)
__global__ __launch_bounds__(256) void k_precompute(
    const float* __restrict__ ldt, const float* __restrict__ lar,
    const float* __restrict__ aim, const float* __restrict__ cre,
    const float* __restrict__ cim, float4* __restrict__ lwc,
    float2* __restrict__ wt) {
    int idx = blockIdx.x * 256 + threadIdx.x;      // [4][512][32]
    int i = idx >> 14;
    int h = (idx >> 5) & 511;
    int n = idx & 31;
    float dt = expf(ldt[i * 512 + h]);
    float Are = -expf(lar[idx]);
    float Aim = aim[idx];
    float dre = dt * Are, dim = dt * Aim;
    float e = expf(dre);
    float wre = e * cosf(dim);
    float wim = e * sinf(dim);
    float emr = wre - 1.f, emi = wim;              // expm1(dtA)
    float inv = 1.f / (Are * Are + Aim * Aim);
    float fr = (emr * Are + emi * Aim) * inv;      // expm1(dtA)/A
    float fi = (emi * Are - emr * Aim) * inv;
    float cr = cre[idx], ci = cim[idx];
    float4 o;
    o.x = wre; o.y = wim;
    o.z = 2.f * (cr * fr - ci * fi);
    o.w = 2.f * (cr * fi + ci * fr);
    int oidx = (i * 32 + n) * 512 + h;             // [layer][n][ch]
    lwc[oidx] = o;
    float ar = wre, ai = wim;                      // w^128 by 7 squarings
#pragma unroll
    for (int k = 0; k < 7; ++k) {
        float nr = ar * ar - ai * ai;
        float ni = 2.f * ar * ai;
        ar = nr; ai = ni;
    }
    wt[oidx] = make_float2(ar, ai);
}

// ---------------- quantize (round-half-even) + transpose (B,C,L)f32 -> (J,C) bf16 ----
__global__ __launch_bounds__(256) void k_quant_transpose(
    const float* __restrict__ x, unsigned short* __restrict__ xq, int b0) {
    __shared__ unsigned short tile[64][65];
    const int bg = b0 + blockIdx.z, bl = blockIdx.z;
    const int c0 = blockIdx.y * 64, t0 = blockIdx.x * 64;
#pragma unroll
    for (int it = 0; it < 16; ++it) {
        int idx = it * 256 + threadIdx.x;
        int r = idx >> 6, cc = idx & 63;
        float f = x[(size_t)(bg * 512 + c0 + r) * 2048 + t0 + cc];
        float q = rintf(f * 64.f) * 0.015625f;     // jnp.round = half-to-even
        tile[r][cc] = f2bf(q);
    }
    __syncthreads();
#pragma unroll
    for (int it = 0; it < 16; ++it) {
        int idx = it * 256 + threadIdx.x;
        int r = idx >> 6, cc = idx & 63;           // r = t-local, cc = c-local
        xq[(size_t)(bl * 2048 + t0 + r) * 512 + c0 + cc] = tile[cc][r];
    }
}

// ---------------- bf16 MFMA GEMM: C[m,j] = sum_k A[m,k]*Bm[j,k], K=512 ---------------
// MODE 0: relu -> hf f32 (j,512)      MODE 2: relu -> d_out f32 (B,512,L)
template <int MODE>
__global__ __launch_bounds__(256, 2) void k_gemm(
    const unsigned short* __restrict__ A, const unsigned short* __restrict__ Bm,
    float* __restrict__ of32, int b0) {
    __shared__ __align__(16) unsigned short Al[128 * 72];
    __shared__ __align__(16) unsigned short Bl[128 * 72];
    const int tid = threadIdx.x;
    const int m0 = blockIdx.x * 128;
    const int j0 = blockIdx.y * 128;
    const int sub = tid & 7;
    const int row = tid >> 3;
    const unsigned short* Ag = A + (size_t)(m0 + row) * 512 + sub * 8;
    const unsigned short* Bg = Bm + (size_t)(j0 + row) * 512 + sub * 8;
    intx4 ra[4], rb[4];
#pragma unroll
    for (int i = 0; i < 4; ++i) {
        ra[i] = *(const intx4*)(Ag + (size_t)i * 32 * 512);
        rb[i] = *(const intx4*)(Bg + (size_t)i * 32 * 512);
    }
    const int lane = tid & 63;
    const int w = tid >> 6;
    const int wm = w & 1, wn = w >> 1;
    const int l15 = lane & 15, quad = lane >> 4;
    floatx4 acc[4][4] = {};
    for (int kt = 0; kt < 8; ++kt) {
#pragma unroll
        for (int i = 0; i < 4; ++i) {
            *(intx4*)(Al + (row + 32 * i) * 72 + sub * 8) = ra[i];
            *(intx4*)(Bl + (row + 32 * i) * 72 + sub * 8) = rb[i];
        }
        __syncthreads();
        if (kt < 7) {
#pragma unroll
            for (int i = 0; i < 4; ++i) {
                ra[i] = *(const intx4*)(Ag + (size_t)i * 32 * 512 + (kt + 1) * 64);
                rb[i] = *(const intx4*)(Bg + (size_t)i * 32 * 512 + (kt + 1) * 64);
            }
        }
#pragma unroll
        for (int ks = 0; ks < 2; ++ks) {
            short8 af[4], bfr[4];
#pragma unroll
            for (int mt = 0; mt < 4; ++mt)
                af[mt] = *(const short8*)(Al + (wm * 64 + mt * 16 + l15) * 72 + ks * 32 + quad * 8);
#pragma unroll
            for (int nt = 0; nt < 4; ++nt)
                bfr[nt] = *(const short8*)(Bl + (wn * 64 + nt * 16 + l15) * 72 + ks * 32 + quad * 8);
#pragma unroll
            for (int mt = 0; mt < 4; ++mt)
#pragma unroll
                for (int nt = 0; nt < 4; ++nt)
                    acc[mt][nt] = __builtin_amdgcn_mfma_f32_16x16x32_bf16(
                        af[mt], bfr[nt], acc[mt][nt], 0, 0, 0);
        }
        __syncthreads();
    }
#pragma unroll
    for (int mt = 0; mt < 4; ++mt) {
#pragma unroll
        for (int nt = 0; nt < 4; ++nt) {
            const int d = m0 + wm * 64 + mt * 16 + quad * 4;   // C/D row = quad*4+reg
            const int j = j0 + wn * 64 + nt * 16 + l15;        // C/D col = lane&15
            floatx4 v = acc[mt][nt];
            if (MODE == 0) {
#pragma unroll
                for (int r = 0; r < 4; ++r) v[r] = relu_keepnan(v[r]);
                *(floatx4*)(of32 + (size_t)j * 512 + d) = v;
            } else {
                const int bl = j >> 11, t = j & 2047;
#pragma unroll
                for (int r = 0; r < 4; ++r)
                    of32[((size_t)((b0 + bl) * 512 + d + r)) * 2048 + t] = relu_keepnan(v[r]);
            }
        }
    }
}

// ------- fused W_out GEMM + GLU: g_out[j,d] = (a+b1)*sigmoid(g+b2), both halves ------
__global__ __launch_bounds__(256, 2) void k_gemm_glu(
    const unsigned short* __restrict__ A,   // W_out layer (1024,512) bf16
    const unsigned short* __restrict__ Bm,  // vb (J,512) bf16
    const float* __restrict__ bias,         // b_out layer (1024) f32
    float* __restrict__ g_out) {            // (J,512) f32
    __shared__ __align__(16) unsigned short A1l[128 * 72];
    __shared__ __align__(16) unsigned short A2l[128 * 72];
    __shared__ __align__(16) unsigned short Bl[64 * 72];
    const int tid = threadIdx.x;
    const int m0 = blockIdx.x * 128;
    const int j0 = blockIdx.y * 64;
    const int sub = tid & 7;
    const int row = tid >> 3;                        // 0..31
    const unsigned short* A1g = A + (size_t)(m0 + row) * 512 + sub * 8;
    const unsigned short* A2g = A1g + 512 * 512;
    const unsigned short* Bg = Bm + (size_t)(j0 + row) * 512 + sub * 8;
    intx4 ra1[4], ra2[4], rb[2];
#pragma unroll
    for (int i = 0; i < 4; ++i) {
        ra1[i] = *(const intx4*)(A1g + (size_t)i * 32 * 512);
        ra2[i] = *(const intx4*)(A2g + (size_t)i * 32 * 512);
    }
#pragma unroll
    for (int i = 0; i < 2; ++i)
        rb[i] = *(const intx4*)(Bg + (size_t)i * 32 * 512);
    const int lane = tid & 63;
    const int w = tid >> 6;
    const int wm = w & 1, wn = w >> 1;               // 2x2 waves: m 2x64, n 2x32
    const int l15 = lane & 15, quad = lane >> 4;
    floatx4 ac1[4][2] = {}, ac2[4][2] = {};
    for (int kt = 0; kt < 8; ++kt) {
#pragma unroll
        for (int i = 0; i < 4; ++i) {
            *(intx4*)(A1l + (row + 32 * i) * 72 + sub * 8) = ra1[i];
            *(intx4*)(A2l + (row + 32 * i) * 72 + sub * 8) = ra2[i];
        }
#pragma unroll
        for (int i = 0; i < 2; ++i)
            *(intx4*)(Bl + (row + 32 * i) * 72 + sub * 8) = rb[i];
        __syncthreads();
        if (kt < 7) {
#pragma unroll
            for (int i = 0; i < 4; ++i) {
                ra1[i] = *(const intx4*)(A1g + (size_t)i * 32 * 512 + (kt + 1) * 64);
                ra2[i] = *(const intx4*)(A2g + (size_t)i * 32 * 512 + (kt + 1) * 64);
            }
#pragma unroll
            for (int i = 0; i < 2; ++i)
                rb[i] = *(const intx4*)(Bg + (size_t)i * 32 * 512 + (kt + 1) * 64);
        }
#pragma unroll
        for (int ks = 0; ks < 2; ++ks) {
            short8 af1[4], af2[4], bfr[2];
#pragma unroll
            for (int mt = 0; mt < 4; ++mt) {
                af1[mt] = *(const short8*)(A1l + (wm * 64 + mt * 16 + l15) * 72 + ks * 32 + quad * 8);
                af2[mt] = *(const short8*)(A2l + (wm * 64 + mt * 16 + l15) * 72 + ks * 32 + quad * 8);
            }
#pragma unroll
            for (int nt = 0; nt < 2; ++nt)
                bfr[nt] = *(const short8*)(Bl + (wn * 32 + nt * 16 + l15) * 72 + ks * 32 + quad * 8);
#pragma unroll
            for (int mt = 0; mt < 4; ++mt)
#pragma unroll
                for (int nt = 0; nt < 2; ++nt) {
                    ac1[mt][nt] = __builtin_amdgcn_mfma_f32_16x16x32_bf16(
                        af1[mt], bfr[nt], ac1[mt][nt], 0, 0, 0);
                    ac2[mt][nt] = __builtin_amdgcn_mfma_f32_16x16x32_bf16(
                        af2[mt], bfr[nt], ac2[mt][nt], 0, 0, 0);
                }
        }
        __syncthreads();
    }
#pragma unroll
    for (int mt = 0; mt < 4; ++mt) {
#pragma unroll
        for (int nt = 0; nt < 2; ++nt) {
            const int d = m0 + wm * 64 + mt * 16 + quad * 4;
            const int j = j0 + wn * 32 + nt * 16 + l15;
            floatx4 v;
#pragma unroll
            for (int r = 0; r < 4; ++r) {
                float a = ac1[mt][nt][r] + bias[d + r];
                float g = ac2[mt][nt][r] + bias[512 + d + r];
                v[r] = a / (1.f + expf(-g));
            }
            *(floatx4*)(g_out + (size_t)j * 512 + d) = v;
        }
    }
}

// ============ segmented S4D scan: 16 states/lane, 32 channels/wave ===================
// 16 segments x 128 steps; 4096 waves (4/SIMD at <=128 VGPR). 4-deep u prefetch.
// lane = half*32 + chl: channel chb*32+chl, states n = half*16 + [0,16).
// Phase A local end-state p; phase C exclusive segment prefix; phase B apply+gelu.

__global__ __launch_bounds__(256, 4) void k_scan_state(
    const float* __restrict__ hbuf, const float4* __restrict__ lwc,
    float2* __restrict__ p, int layer) {
    const int wid = (blockIdx.x << 2) + (threadIdx.x >> 6);
    const int lane = threadIdx.x & 63;
    const int seg = wid & 15, chb = (wid >> 4) & 15, b = wid >> 8;
    const int chl = lane & 31, half = lane >> 5;
    const int ch = chb * 32 + chl;
    const int n0 = half * 16;
    float wre[16], wim[16], sre[16], sim[16];
    const float4* wp = lwc + (size_t)(layer * 32 + n0) * 512 + ch;
#pragma unroll
    for (int n = 0; n < 16; ++n) {
        float4 v = wp[n * 512];
        wre[n] = v.x; wim[n] = v.y; sre[n] = 0.f; sim[n] = 0.f;
    }
    const float* ub = hbuf + ((size_t)b * 2048 + seg * 128) * 512 + ch;
    float ubuf[4];
#pragma unroll
    for (int k = 0; k < 4; ++k) ubuf[k] = ub[k * 512];
    for (int t4 = 0; t4 < 128; t4 += 4) {
        float unx[4];
        if (t4 + 4 < 128) {
#pragma unroll
            for (int k = 0; k < 4; ++k) unx[k] = ub[(t4 + 4 + k) * 512];
        }
#pragma unroll
        for (int k = 0; k < 4; ++k) {
            float u = ubuf[k];
#pragma unroll
            for (int n = 0; n < 16; ++n) {
                float t1 = fmaf(-wim[n], sim[n], u);
                float nr = fmaf(wre[n], sre[n], t1);
                float ni = fmaf(wim[n], sre[n], wre[n] * sim[n]);
                sre[n] = nr; sim[n] = ni;
            }
        }
#pragma unroll
        for (int k = 0; k < 4; ++k) ubuf[k] = unx[k];
    }
    float2* pp = p + (((size_t)(b * 16 + seg) * 32 + n0) * 512) + ch;
#pragma unroll
    for (int n = 0; n < 16; ++n) pp[n * 512] = make_float2(sre[n], sim[n]);
}

// thread -> (b, n, ch): s0[g] = w128*s0[g-1] + p[g-1], exclusive
__global__ __launch_bounds__(256) void k_scan_comb(
    const float2* __restrict__ p, const float2* __restrict__ wt,
    float2* __restrict__ s0, int layer) {
    const int tid = blockIdx.x * 256 + threadIdx.x;
    const int ch = tid & 511, n = (tid >> 9) & 31, b = tid >> 14;
    const float2 wv = wt[(layer * 32 + n) * 512 + ch];
    const size_t base = ((size_t)(b * 16) * 32 + n) * 512 + ch;
    float ar = 0.f, ai = 0.f;
#pragma unroll
    for (int g = 0; g < 16; ++g) {
        s0[base + (size_t)g * 16384] = make_float2(ar, ai);
        float2 pv = p[base + (size_t)g * 16384];
        float nr = fmaf(wv.x, ar, fmaf(-wv.y, ai, pv.x));
        float ni = fmaf(wv.x, ai, fmaf(wv.y, ar, pv.y));
        ar = nr; ai = ni;
    }
}

__global__ __launch_bounds__(256, 4) void k_scan_apply(
    const float* __restrict__ hbuf, const float4* __restrict__ lwc,
    const float2* __restrict__ s0, const float* __restrict__ Dp,
    unsigned short* __restrict__ vout, int layer) {
    const int wid = (blockIdx.x << 2) + (threadIdx.x >> 6);
    const int lane = threadIdx.x & 63;
    const int seg = wid & 15, chb = (wid >> 4) & 15, b = wid >> 8;
    const int chl = lane & 31, half = lane >> 5;
    const int ch = chb * 32 + chl;
    const int n0 = half * 16;
    float wre[16], wim[16], sre[16], sim[16], c2re[16], c2in[16];
    const float4* wp = lwc + (size_t)(layer * 32 + n0) * 512 + ch;
    const float2* sp = s0 + (((size_t)(b * 16 + seg) * 32 + n0) * 512) + ch;
#pragma unroll
    for (int n = 0; n < 16; ++n) {
        float4 v = wp[n * 512];
        wre[n] = v.x; wim[n] = v.y; c2re[n] = v.z; c2in[n] = -v.w;
        float2 sv = sp[n * 512];
        sre[n] = sv.x; sim[n] = sv.y;
    }
    const float Dh = Dp[layer * 512 + ch];
    const float* ub = hbuf + ((size_t)b * 2048 + seg * 128) * 512 + ch;
    unsigned short* vb = vout + ((size_t)b * 2048 + seg * 128) * 512 + ch;
    float ubuf[4];
#pragma unroll
    for (int k = 0; k < 4; ++k) ubuf[k] = ub[k * 512];
    for (int t4 = 0; t4 < 128; t4 += 4) {
        float unx[4];
        if (t4 + 4 < 128) {
#pragma unroll
            for (int k = 0; k < 4; ++k) unx[k] = ub[(t4 + 4 + k) * 512];
        }
#pragma unroll
        for (int k = 0; k < 4; ++k) {
            float u = ubuf[k];
            float y = 0.f;
#pragma unroll
            for (int n = 0; n < 16; ++n) {
                float t1 = fmaf(-wim[n], sim[n], u);
                float nr = fmaf(wre[n], sre[n], t1);
                float ni = fmaf(wim[n], sre[n], wre[n] * sim[n]);
                sre[n] = nr; sim[n] = ni;
                y = fmaf(c2re[n], nr, y);
                y = fmaf(c2in[n], ni, y);
            }
            y += __shfl_xor(y, 32, 64);        // merge the two 16-state half-dots
            y = fmaf(Dh, u, y);
            float g = 0.5f * y * (1.f + erff(y * 0.70710678118654752f));
            if (half == 0) vb[(t4 + k) * 512] = f2bf(g);
        }
#pragma unroll
        for (int k = 0; k < 4; ++k) ubuf[k] = unx[k];
    }
}

// ---------------- residual + LayerNorm over channels (g already GLU'd) ---------------
__global__ __launch_bounds__(256, 4) void k_res_ln(
    const float* __restrict__ g, float* __restrict__ hf, unsigned short* __restrict__ hb,
    const float* __restrict__ lng, const float* __restrict__ lnb,
    int layer, int wbf) {
    __shared__ float r1[4], r2[4];
    const size_t j = blockIdx.x;
    const float* gj = g + j * 512;
    float* hj = hf + j * 512;
    const int tid = threadIdx.x, lane = tid & 63, w = tid >> 6;
    float hn[2], s1 = 0.f, s2 = 0.f;
#pragma unroll
    for (int q = 0; q < 2; ++q) {
        int d = tid + q * 256;
        float v = gj[d] + hj[d];                  // residual
        hn[q] = v; s1 += v; s2 += v * v;
    }
#pragma unroll
    for (int m = 32; m >= 1; m >>= 1) { s1 += __shfl_xor(s1, m, 64); s2 += __shfl_xor(s2, m, 64); }
    if (lane == 0) { r1[w] = s1; r2[w] = s2; }
    __syncthreads();
    const float S1 = r1[0] + r1[1] + r1[2] + r1[3];
    const float S2 = r2[0] + r2[1] + r2[2] + r2[3];
    const float mu = S1 * (1.f / 512.f);
    const float var = S2 * (1.f / 512.f) - mu * mu;
    const float isd = 1.f / sqrtf(var + 1e-5f);
#pragma unroll
    for (int q = 0; q < 2; ++q) {
        int d = tid + q * 256;
        float o = (hn[q] - mu) * isd * lng[layer * 512 + d] + lnb[layer * 512 + d];
        hj[d] = o;
        if (wbf) hb[j * 512 + d] = f2bf(o);
    }
}

extern "C" void kernel_launch(void* const* d_in, const int* in_sizes, int n_in,
                              void* d_out, int out_size, void* d_ws, size_t ws_size,
                              hipStream_t stream) {
    (void)in_sizes; (void)n_in; (void)out_size;
    const float* x      = (const float*)d_in[0];
    const float* W_enc  = (const float*)d_in[1];
    const float* W_dec  = (const float*)d_in[2];
    const float* log_dt = (const float*)d_in[3];
    const float* log_Ar = (const float*)d_in[4];
    const float* A_im   = (const float*)d_in[5];
    const float* C_re   = (const float*)d_in[6];
    const float* C_im   = (const float*)d_in[7];
    const float* Dp     = (const float*)d_in[8];
    const float* W_out  = (const float*)d_in[9];
    const float* b_out  = (const float*)d_in[10];
    const float* ln_g   = (const float*)d_in[11];
    const float* ln_b   = (const float*)d_in[12];

    // fixed: lwc 1MiB + wt 0.5MiB + bf16 weights ~5MiB; per batch elem 10MiB
    int C = 16;
    while (C > 1 && (size_t)C * (10ull << 20) + (8ull << 20) > ws_size) C >>= 1;
    const size_t J = (size_t)C * 2048;

    char* ws = (char*)d_ws;
    size_t off = 0;
    auto alloc = [&](size_t bytes) { void* p = ws + off; off += (bytes + 255) & ~(size_t)255; return p; };
    float4*         lwc   = (float4*)alloc(4ull * 512 * 32 * 16);
    float2*         wt    = (float2*)alloc(4ull * 512 * 32 * 8);
    unsigned short* wencb = (unsigned short*)alloc(512 * 512 * 2);
    unsigned short* wdecb = (unsigned short*)alloc(512 * 512 * 2);
    unsigned short* woutb = (unsigned short*)alloc(4ull * 1024 * 512 * 2);
    float*          g     = (float*)alloc(J * 512 * 4);          // GLU out (xq/p/s0 alias)
    float*          hf    = (float*)alloc(J * 512 * 4);          // h, f32
    unsigned short* vb    = (unsigned short*)alloc(J * 512 * 2); // gelu out bf16 (hb alias)
    unsigned short* xq    = (unsigned short*)g;                  // dead after encoder GEMM
    unsigned short* hb    = vb;                                  // vb dead after layer-3 GEMM
    // scan scratch aliases g (dead during scan): p = C*2MiB, s0 = C*2MiB = exactly g
    float2*         p     = (float2*)g;
    float2*         s0    = (float2*)(g + (size_t)C * 524288);

    k_precompute<<<256, 256, 0, stream>>>(log_dt, log_Ar, A_im, C_re, C_im, lwc, wt);
    k_cvt<<<1024, 256, 0, stream>>>(W_enc, wencb, 512 * 512);
    k_cvt<<<1024, 256, 0, stream>>>(W_dec, wdecb, 512 * 512);
    k_cvt<<<8192, 256, 0, stream>>>(W_out, woutb, 4 * 1024 * 512);
    for (int b0 = 0; b0 < 16; b0 += C) {
        k_quant_transpose<<<dim3(32, 8, C), 256, 0, stream>>>(x, xq, b0);
        k_gemm<0><<<dim3(4, C * 16), 256, 0, stream>>>(wencb, xq, hf, 0);
        for (int i = 0; i < 4; ++i) {
            k_scan_state<<<C * 64, 256, 0, stream>>>(hf, lwc, p, i);
            k_scan_comb<<<C * 64, 256, 0, stream>>>(p, wt, s0, i);
            k_scan_apply<<<C * 64, 256, 0, stream>>>(hf, lwc, s0, Dp, vb, i);
            k_gemm_glu<<<dim3(4, C * 32), 256, 0, stream>>>(
                woutb + (size_t)i * 1024 * 512, vb, b_out + (size_t)i * 1024, g);
            k_res_ln<<<C * 2048, 256, 0, stream>>>(g, hf, hb, ln_g, ln_b, i, (i == 3) ? 1 : 0);
        }
        k_gemm<2><<<dim3(4, C * 16), 256, 0, stream>>>(wdecb, hb, (float*)d_out, b0);
    }
}